// Round 3
// baseline (210.400 us; speedup 1.0000x reference)
//
#include <hip/hip_runtime.h>
#include <hip/hip_bf16.h>

typedef __bf16 bf16;
typedef __attribute__((ext_vector_type(8)))  __bf16 bf16x8;
typedef __attribute__((ext_vector_type(16))) float  f32x16;

#define B_   512
#define NC_  512
#define K_   4
#define S_   8
#define H_   128
#define D_   64
#define XROW (NC_ * K_)          // 2048 ints per batch item

// pi: swap bits 2 and 3 of a within-32 index (involution).
// Hidden dims are stored physically permuted so that the 32x32 MFMA C/D
// register layout of layer k IS the B-fragment layout of layer k+1.
static __device__ __forceinline__ int swap23(int v) {
    return (v & ~12) | ((v & 4) << 1) | ((v & 8) >> 1);
}

__global__ __launch_bounds__(256, 1)
void jt_mlp_kernel(const int*   __restrict__ x,
                   const float* __restrict__ W1g, const float* __restrict__ b1g,
                   const float* __restrict__ W2g, const float* __restrict__ b2g,
                   const float* __restrict__ W3g, const float* __restrict__ b3g,
                   float* __restrict__ out)
{
    const int tid  = threadIdx.x;
    const int lane = tid & 63;
    const int w    = tid >> 6;      // wave 0..3: items [w*128, w*128+128)
    const int l31  = lane & 31;
    const int lhi  = lane >> 5;     // 0/1
    const int kk   = l31 & 3;       // within-item variable position k
    const int n    = blockIdx.x;    // clique

    const float* W1p = W1g + (size_t)n * (D_ * H_);
    const float* W2p = W2g + (size_t)n * (H_ * H_);
    const float* W3p = W3g + (size_t)n * (H_ * S_);
    const float* b1p = b1g + n * H_;
    const float* b2p = b2g + n * S_ * 0 + n * H_;   // b2 is [NC,H]
    const float* b3p = b3g + n * S_;

    const int p31 = swap23(l31);    // logical column this lane's phys slot maps to

    const bf16 one  = (bf16)1.0f;
    const bf16 zero = (bf16)0.0f;

    // ---------------- register-resident weight fragments ----------------
    // 32x32x16 A-layout: lane holds A[m=lane&31][k=(lane>>5)*8+j]
    // L1: A[m=physH, k=d(logical)] = W1[d][pi(physH)]  (+ b1 folded into d=0..7)
    bf16x8 w1f[4][4];
#pragma unroll
    for (int a = 0; a < 4; ++a) {
        const int pc = 32 * a + p31;
        const float bb = b1p[pc];
#pragma unroll
        for (int kt = 0; kt < 4; ++kt)
#pragma unroll
            for (int j = 0; j < 8; ++j) {
                const int k = kt * 16 + lhi * 8 + j;
                float v = W1p[k * H_ + pc];
                if (kt == 0) {
                    // parent-var-0 block carries the bias: any one-hot in that
                    // block fires it exactly once. Root (n==0) uses a synthetic
                    // state-0 one-hot against a b1-only fragment.
                    const float vb = (n > 0 ? v : 0.f) + bb;
                    v = lhi ? v : vb;
                }
                w1f[a][kt][j] = (bf16)v;
            }
    }
    // L2: A[m=physH, k=logical h1 dim] = W2[k][pi(physH)]; bias tile at k=128
    bf16x8 w2f[4][8], w2b[4];
#pragma unroll
    for (int a = 0; a < 4; ++a) {
        const int pc = 32 * a + p31;
#pragma unroll
        for (int kt = 0; kt < 8; ++kt)
#pragma unroll
            for (int j = 0; j < 8; ++j)
                w2f[a][kt][j] = (bf16)W2p[(kt * 16 + lhi * 8 + j) * H_ + pc];
#pragma unroll
        for (int j = 0; j < 8; ++j) w2b[a][j] = zero;
        w2b[a][0] = lhi ? zero : (bf16)b2p[pc];
    }
    // L3: A[m=state, k=logical h2 dim] = W3[k][state] (states not permuted)
    bf16x8 w3f[8], w3b;
#pragma unroll
    for (int kt = 0; kt < 8; ++kt)
#pragma unroll
        for (int j = 0; j < 8; ++j)
            w3f[kt][j] = (l31 < S_) ? (bf16)W3p[(kt * 16 + lhi * 8 + j) * S_ + l31]
                                    : zero;
#pragma unroll
    for (int j = 0; j < 8; ++j) w3b[j] = zero;
    w3b[0] = (l31 < S_ && !lhi) ? (bf16)b3p[l31] : zero;

    // constant-1 B-frag hitting only k-slot (lhi=0, j=0) -> the bias tiles
    bf16x8 onef;
#pragma unroll
    for (int j = 0; j < 8; ++j) onef[j] = zero;
    onef[0] = lhi ? zero : one;

    f32x16 zf;
#pragma unroll
    for (int i = 0; i < 16; ++i) zf[i] = 0.f;

    // ---------------- x prefetch for chunk 0 ----------------
    int4 xo_c, xp_c;
    {
        const int item0 = w * 128 + (l31 >> 2);
        const int* xb = x + (size_t)item0 * XROW + n * K_;
        xo_c = *(const int4*)xb;
        xp_c = (n > 0) ? *(const int4*)(xb - K_) : make_int4(0, 0, 0, 0);
    }

#pragma unroll 1
    for (int c = 0; c < 16; ++c) {
        const int item = w * 128 + c * 8 + (l31 >> 2);
        const int4 xo = xo_c, xp = xp_c;
        if (c < 15) {                    // prefetch next chunk's x
            const int* xb = x + (size_t)(item + 8) * XROW + n * K_;
            xo_c = *(const int4*)xb;
            xp_c = (n > 0) ? *(const int4*)(xb - K_) : make_int4(0, 0, 0, 0);
        }

        // ---- one-hot B-frags straight from x (segment g = 2*kt + lhi) ----
        int sel[4];
        sel[0] = (n > 0) ? (lhi ? xp.y : xp.x) : (lhi ? -1 : 0);
        sel[1] = (n > 0) ? (lhi ? xp.w : xp.z) : -1;
        sel[2] = (kk > (lhi ? 1 : 0)) ? (lhi ? xo.y : xo.x) : -1;  // var lhi
        sel[3] = (kk > (lhi ? 3 : 2)) ? (lhi ? xo.w : xo.z) : -1;  // var 2+lhi
        bf16x8 bf1[4];
#pragma unroll
        for (int kt = 0; kt < 4; ++kt)
#pragma unroll
            for (int j = 0; j < 8; ++j)
                bf1[kt][j] = (sel[kt] == j) ? one : zero;

        // ---------------- layer 1 ----------------
        f32x16 A[4];
#pragma unroll
        for (int a = 0; a < 4; ++a) A[a] = zf;
#pragma unroll
        for (int kt = 0; kt < 4; ++kt)
#pragma unroll
            for (int a = 0; a < 4; ++a)
                A[a] = __builtin_amdgcn_mfma_f32_32x32x16_bf16(w1f[a][kt], bf1[kt], A[a], 0, 0, 0);

        // ---------------- layer 2 (B-frag = relu of 8 consecutive acc regs) ----------------
        f32x16 Cc[4];
#pragma unroll
        for (int a = 0; a < 4; ++a) Cc[a] = zf;
#pragma unroll
        for (int kt = 0; kt < 8; ++kt) {
            bf16x8 hf;
#pragma unroll
            for (int j = 0; j < 8; ++j)
                hf[j] = (bf16)fmaxf(A[kt >> 1][8 * (kt & 1) + j], 0.f);
#pragma unroll
            for (int a = 0; a < 4; ++a)
                Cc[a] = __builtin_amdgcn_mfma_f32_32x32x16_bf16(w2f[a][kt], hf, Cc[a], 0, 0, 0);
        }
#pragma unroll
        for (int a = 0; a < 4; ++a)
            Cc[a] = __builtin_amdgcn_mfma_f32_32x32x16_bf16(w2b[a], onef, Cc[a], 0, 0, 0);

        // ---------------- layer 3 ----------------
        f32x16 L = zf;
#pragma unroll
        for (int kt = 0; kt < 8; ++kt) {
            bf16x8 hf;
#pragma unroll
            for (int j = 0; j < 8; ++j)
                hf[j] = (bf16)fmaxf(Cc[kt >> 1][8 * (kt & 1) + j], 0.f);
            L = __builtin_amdgcn_mfma_f32_32x32x16_bf16(w3f[kt], hf, L, 0, 0, 0);
        }
        L = __builtin_amdgcn_mfma_f32_32x32x16_bf16(w3b, onef, L, 0, 0, 0);
        // D: col = l31 = batch row; regs 0..3 = states 4*lhi .. 4*lhi+3

        // ---------------- register log-softmax + gather + sum over K ----------------
        float m4 = fmaxf(fmaxf(L[0], L[1]), fmaxf(L[2], L[3]));
        const float mm = fmaxf(m4, __shfl_xor(m4, 32));
        float e = __expf(L[0] - mm) + __expf(L[1] - mm) +
                  __expf(L[2] - mm) + __expf(L[3] - mm);
        const float ssum = e + __shfl_xor(e, 32);
        const int xs = (kk & 2) ? ((kk & 1) ? xo.w : xo.z)
                                : ((kk & 1) ? xo.y : xo.x);
        const float own = (xs & 2) ? ((xs & 1) ? L[3] : L[2])
                                   : ((xs & 1) ? L[1] : L[0]);
        const float oth = __shfl_xor(own, 32);
        const float obs = ((xs >> 2) == lhi) ? own : oth;
        float lp = obs - mm - __logf(ssum);
        lp += __shfl_xor(lp, 1);
        lp += __shfl_xor(lp, 2);
        if (lhi == 0 && kk == 0)
            out[(size_t)item * NC_ + n] = lp;
    }
}

extern "C" void kernel_launch(void* const* d_in, const int* in_sizes, int n_in,
                              void* d_out, int out_size, void* d_ws, size_t ws_size,
                              hipStream_t stream) {
    const int*   x  = (const int*)d_in[0];
    const float* W1 = (const float*)d_in[1];
    const float* b1 = (const float*)d_in[2];
    const float* W2 = (const float*)d_in[3];
    const float* b2 = (const float*)d_in[4];
    const float* W3 = (const float*)d_in[5];
    const float* b3 = (const float*)d_in[6];
    float* out = (float*)d_out;
    jt_mlp_kernel<<<dim3(NC_), 256, 0, stream>>>(x, W1, b1, W2, b2, W3, b3, out);
}